// Round 5
// baseline (162.619 us; speedup 1.0000x reference)
//
#include <hip/hip_runtime.h>

#define DEV static __device__ __forceinline__

typedef __attribute__((ext_vector_type(4))) float f32x4;
typedef __attribute__((ext_vector_type(16))) float f32x16;
typedef __attribute__((ext_vector_type(8))) __bf16 bfv8;
typedef __attribute__((ext_vector_type(8))) short s8v;
typedef __attribute__((ext_vector_type(4))) short s4v;
typedef __attribute__((ext_vector_type(4))) unsigned u32x4;

DEV short f2bf(float f) {
    unsigned u = __float_as_uint(f);
    u = (u + 0x7fffu + ((u >> 16) & 1u)) >> 16;
    return (short)u;
}
DEV float bf2f(short s) { return __uint_as_float(((unsigned)(unsigned short)s) << 16); }

DEV void gload16(const void* g, void* l) {
    __builtin_amdgcn_global_load_lds(
        (const __attribute__((address_space(1))) void*)g,
        (__attribute__((address_space(3))) void*)l, 16, 0, 0);
}

DEV f32x4 mfma16(bfv8 a, bfv8 b, f32x4 c) {
    return __builtin_amdgcn_mfma_f32_16x16x32_bf16(a, b, c, 0, 0, 0);
}
DEV f32x16 mfma32(bfv8 a, bfv8 b, f32x16 c) {
    return __builtin_amdgcn_mfma_f32_32x32x16_bf16(a, b, c, 0, 0, 0);
}

DEV float max3f(float a, float b, float c) {
    float d;
    asm("v_max3_f32 %0, %1, %2, %3" : "=v"(d) : "v"(a), "v"(b), "v"(c));
    return d;
}
DEV unsigned cvtpk(float lo, float hi) {
    unsigned w;
    asm("v_cvt_pk_bf16_f32 %0, %1, %2" : "=v"(w) : "v"(lo), "v"(hi));
    return w;
}

// LDS tile layout: [row][8 slots of 8 bf16], physical slot = logical slot ^ (row&7)
DEV bfv8 ldsfrag(const short* base, int row, int slog) {
    int sp = slog ^ (row & 7);
    return *reinterpret_cast<const bfv8*>(base + row * 64 + sp * 8);
}

// ---------------- f32 -> bf16 elementwise (8 elems/thread, exact-fit grid) ----
__global__ void k_cvt(const float* __restrict__ in, short* __restrict__ out, float s) {
    int i = blockIdx.x * blockDim.x + threadIdx.x;
    const float4* p = (const float4*)in + (size_t)i * 2;
    float4 a = p[0], b = p[1];
    s8v o;
    o[0] = f2bf(a.x * s); o[1] = f2bf(a.y * s); o[2] = f2bf(a.z * s); o[3] = f2bf(a.w * s);
    o[4] = f2bf(b.x * s); o[5] = f2bf(b.y * s); o[6] = f2bf(b.z * s); o[7] = f2bf(b.w * s);
    reinterpret_cast<s8v*>(out)[i] = o;
}

// ---------------- all four W [1024x1024] f32 -> Wt [n][k] bf16 (z selects) -----
__global__ void k_transpose4(
    const float* __restrict__ W0, const float* __restrict__ W1,
    const float* __restrict__ W2, const float* __restrict__ W3,
    short* __restrict__ T0, short* __restrict__ T1,
    short* __restrict__ T2, short* __restrict__ T3, float s0)
{
    __shared__ float tl[32][33];
    const int z = blockIdx.z;
    const float* W = z == 0 ? W0 : z == 1 ? W1 : z == 2 ? W2 : W3;
    short* Wt = z == 0 ? T0 : z == 1 ? T1 : z == 2 ? T2 : T3;
    const float s = z == 0 ? s0 : 1.f;
    int tx = threadIdx.x & 31, ty = threadIdx.x >> 5;
    int nb = blockIdx.x * 32, kb = blockIdx.y * 32;
#pragma unroll
    for (int i = 0; i < 4; i++)
        tl[ty + i * 8][tx] = W[(kb + ty + i * 8) * 1024 + nb + tx];
    __syncthreads();
#pragma unroll
    for (int i = 0; i < 4; i++)
        Wt[(nb + ty + i * 8) * 1024 + kb + tx] = f2bf(tl[tx][ty + i * 8] * s);
}

// ---------------- GEMM core (BM=64 BN=128 BK=64, 4 waves 2Mx2N) ---------------
// epi 0: bf16 out [B,H,S,Hd]; epi 1: bf16 out [B,H,Hd,S] (V^T); epi 2: f32 row-major.
template <int EPI>
DEV void gemm_body(const short* __restrict__ A, const short* __restrict__ Bt,
                   const float* __restrict__ bias, void* __restrict__ outp,
                   float bscale, int row0, int col0, short* As, short* Bs)
{
    const int t = threadIdx.x, lane = t & 63;
    const int wv = t >> 6, wr = wv >> 1, wc = wv & 1;
    const int g = lane >> 4, c = lane & 15;

    const f32x4 z4 = {0.f, 0.f, 0.f, 0.f};
    f32x4 acc[2][4];
#pragma unroll
    for (int m = 0; m < 2; m++)
#pragma unroll
        for (int n = 0; n < 4; n++) acc[m][n] = z4;

    for (int kt = 0; kt < 16; ++kt) {
        const int k0 = kt * 64;
        const short* Ag = A + row0 * 1024 + k0;
        const short* Bg = Bt + col0 * 1024 + k0;
#pragma unroll
        for (int j = 0; j < 2; j++) {
            int idx = j * 256 + t;
            int row = idx >> 3, sp = idx & 7, sl = sp ^ (row & 7);
            gload16(Ag + row * 1024 + sl * 8, As + idx * 8);
        }
#pragma unroll
        for (int j = 0; j < 4; j++) {
            int idx = j * 256 + t;
            int row = idx >> 3, sp = idx & 7, sl = sp ^ (row & 7);
            gload16(Bg + row * 1024 + sl * 8, Bs + idx * 8);
        }
        __syncthreads();

        bfv8 af[2][2], bfr[4][2];
#pragma unroll
        for (int m = 0; m < 2; m++)
#pragma unroll
            for (int ks = 0; ks < 2; ks++)
                af[m][ks] = ldsfrag(As, wr * 32 + m * 16 + c, ks * 4 + g);
#pragma unroll
        for (int n = 0; n < 4; n++)
#pragma unroll
            for (int ks = 0; ks < 2; ks++)
                bfr[n][ks] = ldsfrag(Bs, wc * 64 + n * 16 + c, ks * 4 + g);
        __builtin_amdgcn_s_setprio(1);
#pragma unroll
        for (int m = 0; m < 2; m++)
#pragma unroll
            for (int n = 0; n < 4; n++)
#pragma unroll
                for (int ks = 0; ks < 2; ks++)
                    acc[m][n] = mfma16(af[m][ks], bfr[n][ks], acc[m][n]);
        __builtin_amdgcn_s_setprio(0);
        __syncthreads();
    }

    // epilogue: C row = row0 + wr*32 + m*16 + g*4 + r ; col = col0 + wc*64 + n*16 + c
#pragma unroll
    for (int n = 0; n < 4; n++) {
        const int gc = col0 + wc * 64 + n * 16 + c;
        const float bvl = bias[gc] * bscale;
        const int h = gc >> 6, d = gc & 63;
#pragma unroll
        for (int m = 0; m < 2; m++) {
            const int gr = row0 + wr * 32 + m * 16 + g * 4;
            if (EPI == 2) {
                float* O = (float*)outp;
#pragma unroll
                for (int r = 0; r < 4; r++) O[(gr + r) * 1024 + gc] = acc[m][n][r] + bvl;
            } else {
                const int b = gr >> 11, sr = gr & 2047;
                short* O = (short*)outp;
                if (EPI == 0) {
                    int base = ((b * 16 + h) * 2048 + sr) * 64 + d;
#pragma unroll
                    for (int r = 0; r < 4; r++) O[base + r * 64] = f2bf(acc[m][n][r] + bvl);
                } else {
                    s4v vv;
#pragma unroll
                    for (int r = 0; r < 4; r++) vv[r] = f2bf(acc[m][n][r] + bvl);
                    *reinterpret_cast<s4v*>(O + ((b * 16 + h) * 64 + d) * 2048 + sr) = vv;
                }
            }
        }
    }
}

// fused QKV projection: grid (64, 24); y/8 selects Q/K/V
__global__ __launch_bounds__(256, 2) void k_gemm3(
    const short* __restrict__ A,
    const short* __restrict__ WqT, const short* __restrict__ WkT, const short* __restrict__ WvT,
    const float* __restrict__ bq, const float* __restrict__ bk, const float* __restrict__ bv,
    short* __restrict__ Qs, short* __restrict__ Kst, short* __restrict__ Vts, float scq)
{
    __shared__ alignas(16) short As[64 * 64];
    __shared__ alignas(16) short Bs[128 * 64];
    const int which = blockIdx.y >> 3;
    const int col0 = (blockIdx.y & 7) * 128;
    const int row0 = blockIdx.x * 64;
    if (which == 0)
        gemm_body<0>(A, WqT, bq, Qs, scq, row0, col0, As, Bs);
    else if (which == 1)
        gemm_body<0>(A, WkT, bk, Kst, 1.f, row0, col0, As, Bs);
    else
        gemm_body<1>(A, WvT, bv, Vts, 1.f, row0, col0, As, Bs);
}

// final projection
__global__ __launch_bounds__(256, 2) void k_gemmO(
    const short* __restrict__ A, const short* __restrict__ Bt,
    const float* __restrict__ bias, float* __restrict__ outp)
{
    __shared__ alignas(16) short As[64 * 64];
    __shared__ alignas(16) short Bs[128 * 64];
    gemm_body<2>(A, Bt, bias, outp, 1.f, blockIdx.x * 64, blockIdx.y * 128, As, Bs);
}

// ---------------- flash attention, 32x32 MFMA, in-register P (no P-LDS) -------
// Q,K: [B,H,S,64] bf16 (Q pre-scaled by 0.125*log2e), Vt: [B,H,64,S] bf16,
// bb: 0.5*log2e*binding bf16 [S,S].  Ob: [B,S,1024] bf16.
// Grid (16, 32): 4 waves x 32 q-rows = 128 q/block; KV tile = 128, dbuf LDS 64KB.
// Swapped ops: QK^T = mfma(K,Q) -> lane owns q = lane&31; PV = mfma(V^T,P) -> O^T.
// P stays in registers: cvt_pk words + shfl_xor(32) half-exchange feed PV B-frags.
// C/D layout (verified): col = lane&31, row = (reg&3)+8*(reg>>2)+4*(lane>>5).
__global__ __launch_bounds__(256, 2) void k_attn(
    const short* __restrict__ Q, const short* __restrict__ K,
    const short* __restrict__ Vt, const short* __restrict__ bb,
    short* __restrict__ Ob)
{
    __shared__ alignas(16) short Ks[2][128 * 64];   // [k_kv 128][d 64], slot^=(row&7)
    __shared__ alignas(16) short Vs[2][64 * 128];   // [d 64][k_kv 128], slot^=(row&15)
    const int t = threadIdx.x, lane = t & 63;
    const int wv = t >> 6, q = lane & 31, hi = lane >> 5;
    const int qt = blockIdx.x, bh = blockIdx.y;
    const int b = bh >> 4, h = bh & 15;
    const short* Qb = Q + bh * 2048 * 64;
    const short* Kb = K + bh * 2048 * 64;
    const short* Vb = Vt + bh * 64 * 2048;
    const int qg = qt * 128 + wv * 32 + q;        // this lane's global q row
    const int qx7 = q & 7, qx15 = q & 15;

    // Q fragments (B-operand): qf[ks] = Q[qg][16ks + 8hi .. +7]
    bfv8 qf[4];
#pragma unroll
    for (int ks = 0; ks < 4; ks++)
        qf[ks] = *reinterpret_cast<const bfv8*>(Qb + qg * 64 + 16 * ks + 8 * hi);

    f32x16 oa[2];   // O^T d-tiles; elem reg: d = 32dt + (reg&3)+8*(reg>>2)+4hi, col q
#pragma unroll
    for (int dt = 0; dt < 2; dt++)
#pragma unroll
        for (int r = 0; r < 16; r++) oa[dt][r] = 0.f;
    float mrun = 20.0f, lrun = 0.f;   // fixed max-estimate (logits bounded ~|12|)

    // staging pointers (pre-swizzled source, linear LDS dest)
    const short* kp[4]; const short* vp[4];
    int kdst[4], vdst[4];
#pragma unroll
    for (int j = 0; j < 4; j++) {
        int idx = j * 256 + t;
        int kr = idx >> 3, ksl = (idx & 7) ^ (kr & 7);
        kp[j] = Kb + kr * 64 + ksl * 8;
        kdst[j] = idx * 8;
        int vr = idx >> 4, vsl = (idx & 15) ^ (vr & 15);
        vp[j] = Vb + vr * 2048 + vsl * 8;
        vdst[j] = idx * 8;
    }
    auto stage = [&](int buf) {
#pragma unroll
        for (int j = 0; j < 4; j++) {
            gload16(kp[j], &Ks[buf][kdst[j]]);
            gload16(vp[j], &Vs[buf][vdst[j]]);
        }
    };

    // bias prefetch: bn[4t+u] = bb[qg][kt*128 + 32t + 8u + 4hi .. +3]
    const short* bbp = bb + (size_t)qg * 2048 + 4 * hi;
    s4v bn[16];
#pragma unroll
    for (int i = 0; i < 16; i++)
        bn[i] = *reinterpret_cast<const s4v*>(bbp + 32 * (i >> 2) + 8 * (i & 3));

    stage(0);
#pragma unroll
    for (int j = 0; j < 4; j++) { kp[j] += 8192; vp[j] += 128; }
    __syncthreads();

    for (int kt = 0; kt < 16; ++kt) {
        const int cur = kt & 1;
        if (kt < 15) {
            stage(cur ^ 1);
#pragma unroll
            for (int j = 0; j < 4; j++) { kp[j] += 8192; vp[j] += 128; }
        }
        const short* Kc = &Ks[cur][0];
        const short* Vc = &Vs[cur][0];

        // ---- QK^T: 4 C-tiles of 32 k-rows; bias as accumulator init ----
        unsigned W[4][8];
        float lsum = 0.f, pmax = 0.f;
#pragma unroll
        for (int tt = 0; tt < 4; tt++) {
            f32x16 sc;
#pragma unroll
            for (int r = 0; r < 16; r++)
                sc[r] = bf2f(bn[4 * tt + (r >> 2)][r & 3]);
            __builtin_amdgcn_s_setprio(1);
#pragma unroll
            for (int ks = 0; ks < 4; ks++) {
                bfv8 kf = *reinterpret_cast<const bfv8*>(
                    Kc + (32 * tt + q) * 64 + ((2 * ks + hi) ^ qx7) * 8);
                sc = mfma32(kf, qf[ks], sc);
            }
            __builtin_amdgcn_s_setprio(0);
            // speculative exp2 against max-estimate
#pragma unroll
            for (int r = 0; r < 16; r++)
                sc[r] = __builtin_amdgcn_exp2f(sc[r] - mrun);
            // partial sum / max (off critical path)
            float a0 = (sc[0] + sc[1]) + (sc[2] + sc[3]);
            float a1 = (sc[4] + sc[5]) + (sc[6] + sc[7]);
            float a2 = (sc[8] + sc[9]) + (sc[10] + sc[11]);
            float a3 = (sc[12] + sc[13]) + (sc[14] + sc[15]);
            lsum += (a0 + a1) + (a2 + a3);
            float m0 = fmaxf(max3f(sc[0], sc[1], sc[2]), sc[3]);
            float m1 = fmaxf(max3f(sc[4], sc[5], sc[6]), sc[7]);
            float m2 = fmaxf(max3f(sc[8], sc[9], sc[10]), sc[11]);
            float m3 = fmaxf(max3f(sc[12], sc[13], sc[14]), sc[15]);
            pmax = fmaxf(pmax, fmaxf(max3f(m0, m1, m2), m3));
            // pack P words: W[tt][w] = bf16(sc[2w], sc[2w+1])
#pragma unroll
            for (int w = 0; w < 8; w++)
                W[tt][w] = cvtpk(sc[2 * w], sc[2 * w + 1]);
        }

        // bias prefetch for next iter (after last bn consumption)
        if (kt < 15) {
            bbp += 128;
#pragma unroll
            for (int i = 0; i < 16; i++)
                bn[i] = *reinterpret_cast<const s4v*>(bbp + 32 * (i >> 2) + 8 * (i & 3));
        }

        // ---- PV: 8 k-chunks of 16; P B-frags from words + half-exchange ----
#pragma unroll
        for (int j = 0; j < 8; j++) {
            const int tt = j >> 1, e = j & 1;
            unsigned x0 = hi ? W[tt][4 * e + 0] : W[tt][4 * e + 2];
            unsigned x1 = hi ? W[tt][4 * e + 1] : W[tt][4 * e + 3];
            unsigned r0 = (unsigned)__shfl_xor((int)x0, 32);
            unsigned r1 = (unsigned)__shfl_xor((int)x1, 32);
            u32x4 pw;
            pw.x = hi ? r0 : W[tt][4 * e + 0];
            pw.y = hi ? r1 : W[tt][4 * e + 1];
            pw.z = hi ? W[tt][4 * e + 2] : r0;
            pw.w = hi ? W[tt][4 * e + 3] : r1;
            bfv8 pf = __builtin_bit_cast(bfv8, pw);
            __builtin_amdgcn_s_setprio(1);
#pragma unroll
            for (int dt = 0; dt < 2; dt++) {
                bfv8 vf = *reinterpret_cast<const bfv8*>(
                    Vc + (32 * dt + q) * 128 + ((2 * j + hi) ^ qx15) * 8);
                oa[dt] = mfma32(vf, pf, oa[dt]);
            }
            __builtin_amdgcn_s_setprio(0);
        }

        // ---- stats update + deferred-max safety (pe-domain, 2^11.5) ----
        float rs = lsum + __shfl_xor(lsum, 32);
        lrun += rs;
        if (!__all(pmax <= 2896.0f)) {
            float rmax = fmaxf(pmax, __shfl_xor(pmax, 32));
            if (rmax > 2896.0f) {
                const float corr = 1.0f / rmax;
                mrun += __log2f(rmax);
                lrun *= corr;
#pragma unroll
                for (int dt = 0; dt < 2; dt++)
#pragma unroll
                    for (int r = 0; r < 16; r++) oa[dt][r] *= corr;
            }
        }
        __syncthreads();
    }

    // epilogue: O^T -> Ob[B,S,1024], 8B stores; d = 32dt + 8rg + 4hi + r
    const float rl = 1.0f / lrun;
    short* Op = Ob + (size_t)(b * 2048 + qg) * 1024 + h * 64;
#pragma unroll
    for (int dt = 0; dt < 2; dt++)
#pragma unroll
        for (int rg = 0; rg < 4; rg++) {
            s4v st;
#pragma unroll
            for (int r = 0; r < 4; r++) st[r] = f2bf(oa[dt][4 * rg + r] * rl);
            *reinterpret_cast<s4v*>(Op + 32 * dt + 8 * rg + 4 * hi) = st;
        }
}

extern "C" void kernel_launch(void* const* d_in, const int* in_sizes, int n_in,
                              void* d_out, int out_size, void* d_ws, size_t ws_size,
                              hipStream_t stream)
{
    (void)in_sizes; (void)n_in; (void)out_size; (void)ws_size;
    const float* x    = (const float*)d_in[0];
    const float* bind = (const float*)d_in[1];
    const float* Wq   = (const float*)d_in[2];
    const float* bq   = (const float*)d_in[3];
    const float* Wk   = (const float*)d_in[4];
    const float* bk   = (const float*)d_in[5];
    const float* Wv   = (const float*)d_in[6];
    const float* bv   = (const float*)d_in[7];
    const float* Wo   = (const float*)d_in[8];
    const float* bo   = (const float*)d_in[9];

    char* ws = (char*)d_ws;
    const size_t MB = (size_t)1 << 20;
    short* xb   = (short*)(ws + 0 * MB);   // 8 MiB  x as bf16
    short* Wqt  = (short*)(ws + 8 * MB);   // 2 MiB  each, [n][k] bf16
    short* Wkt  = (short*)(ws + 10 * MB);
    short* Wvt  = (short*)(ws + 12 * MB);
    short* Wot  = (short*)(ws + 14 * MB);
    short* bbm  = (short*)(ws + 16 * MB);  // 8 MiB  0.5*log2e*binding bf16
    short* Qs   = (short*)(ws + 24 * MB);  // 8 MiB  [B,H,S,64]
    short* Kst  = (short*)(ws + 32 * MB);  // 8 MiB  [B,H,S,64]
    short* Vts  = (short*)(ws + 40 * MB);  // 8 MiB  [B,H,64,S]
    short* Obuf = (short*)(ws + 48 * MB);  // 8 MiB  [B,S,1024]

    const float LOG2E = 1.4426950408889634f;
    const float SCQ = 0.125f * LOG2E;   // hd^-0.5 * log2e, folded into Wq/bq
    const float SCB = 0.5f * LOG2E;     // binding_bias * log2e

    k_cvt<<<2048, 256, 0, stream>>>(x, xb, 1.f);
    k_cvt<<<2048, 256, 0, stream>>>(bind, bbm, SCB);
    k_transpose4<<<dim3(32, 32, 4), 256, 0, stream>>>(Wq, Wk, Wv, Wo,
                                                      Wqt, Wkt, Wvt, Wot, SCQ);
    k_gemm3<<<dim3(64, 24), 256, 0, stream>>>(xb, Wqt, Wkt, Wvt, bq, bk, bv,
                                              Qs, Kst, Vts, SCQ);
    k_attn<<<dim3(16, 32), 256, 0, stream>>>(Qs, Kst, Vts, bbm, Obuf);
    k_gemmO<<<dim3(64, 8), 256, 0, stream>>>(Obuf, Wot, bo, (float*)d_out);
}